// Round 7
// baseline (359.727 us; speedup 1.0000x reference)
//
#include <hip/hip_runtime.h>

#define DN 96
#define FIN 128

typedef unsigned int uint_t;
typedef unsigned short ushort_t;

typedef __attribute__((ext_vector_type(8))) short short8v;  // 8 bf16 (4 VGPRs)
typedef __attribute__((ext_vector_type(4))) float f32x4;

#define MFMA16 __builtin_amdgcn_mfma_f32_16x16x32_bf16

struct __align__(4) U3 { uint_t x, y, z; };

__device__ __forceinline__ ushort_t f2bf(float f) {
    uint_t u = __float_as_uint(f);
    uint_t r = (u + 0x7FFFu + ((u >> 16) & 1u)) >> 16;
    return (ushort_t)r;
}
__device__ __forceinline__ float bf2f(ushort_t h) { return __uint_as_float(((uint_t)h) << 16); }
__device__ __forceinline__ float bf_lo(uint_t u) { return __uint_as_float(u << 16); }
__device__ __forceinline__ float bf_hi(uint_t u) { return __uint_as_float(u & 0xFFFF0000u); }

__device__ __forceinline__ U3 ldrow(const uint_t* __restrict__ g, int idx, int j) {
    return *(const U3*)(g + (size_t)idx * 48 + 3 * j);
}
__device__ __forceinline__ void acc6(float* s, U3 v) {
    s[0] += bf_lo(v.x); s[1] += bf_hi(v.x);
    s[2] += bf_lo(v.y); s[3] += bf_hi(v.y);
    s[4] += bf_lo(v.z); s[5] += bf_hi(v.z);
}

// ---------- CSR build ----------

__global__ void hist_kernel(const int* __restrict__ ei, const float* __restrict__ ea,
                            int* __restrict__ cnt, uint2* __restrict__ kd, int E, int N) {
    int e = blockIdx.x * 256 + threadIdx.x;
    if (e >= E) return;
    int src = ei[e];
    int dst = ei[E + e];
    int r = (ea[2 * e + 1] > ea[2 * e]) ? 1 : 0;  // argmax over 2, first-max tie -> 0
    kd[e] = make_uint2((uint_t)dst | ((uint_t)r << 16), (uint_t)src);
    atomicAdd(&cnt[r * N + dst], 1);
}

__global__ void offsets_kernel(const int* __restrict__ cnt, int* __restrict__ total,
                               int* __restrict__ rowstart, int* __restrict__ fillptr,
                               int nbins) {
    __shared__ int sd[256];
    __shared__ int sbase;
    int t = threadIdx.x;
    int b = blockIdx.x * 256 + t;
    int v = (b < nbins) ? cnt[b] : 0;
    sd[t] = v;
    __syncthreads();
    for (int off = 1; off < 256; off <<= 1) {
        int add = (t >= off) ? sd[t - off] : 0;
        __syncthreads();
        sd[t] += add;
        __syncthreads();
    }
    if (t == 255) sbase = atomicAdd(total, sd[255]);
    __syncthreads();
    if (b < nbins) {
        int s = sbase + sd[t] - v;  // exclusive
        rowstart[b] = s;
        fillptr[b] = s;
    }
}

// XCD-partitioned fill: srcs writes for a dst range come from one partition of
// blocks -> full-line L2 writebacks instead of 4B/64B amplification.

__global__ __launch_bounds__(256) void fill_part(const uint2* __restrict__ kd,
                            int* __restrict__ fillptr, int* __restrict__ srcs,
                            int E, int N, int PS) {
    int p = blockIdx.x & 7;
    int c = blockIdx.x >> 3;
    int base = c * 2048 + threadIdx.x;
#pragma unroll
    for (int i = 0; i < 8; i++) {
        int e = base + i * 256;
        if (e < E) {
            uint2 v = kd[e];
            int dst = v.x & 0xFFFF;
            if (dst / PS == p) {
                int r = (v.x >> 16) & 1;
                int pos = atomicAdd(&fillptr[r * N + dst], 1);
                srcs[pos] = (int)v.y;
            }
        }
    }
}

// ---------- weight pack: split bf16 hi/lo, MFMA B-fragment layout ----------

__global__ void pack_all(const float* __restrict__ root, const float* __restrict__ W,
                         const float* __restrict__ Wf,
                         ushort_t* __restrict__ Bph, ushort_t* __restrict__ Bpl,
                         ushort_t* __restrict__ Wfh, ushort_t* __restrict__ Wfl) {
    int l = threadIdx.x;      // 0..63
    int bid = blockIdx.x;
    if (bid < 54) {
        int fid = bid;
        int ct = fid / 3, ks = fid % 3;
        int mat = ct / 6, cw = ct % 6;
        const float* M = (mat == 0) ? root : (W + (size_t)(mat - 1) * DN * DN);
        int k0 = 32 * ks + (l >> 4) * 8;
        int col = 16 * cw + (l & 15);
#pragma unroll
        for (int j = 0; j < 8; j++) {
            float v = M[(size_t)(k0 + j) * DN + col];
            ushort_t h = f2bf(v);
            size_t idx = ((size_t)fid * 64 + l) * 8 + j;
            Bph[idx] = h;
            Bpl[idx] = f2bf(v - bf2f(h));
        }
    } else {
        int fid = bid - 54;
        int ct = fid >> 2, ks = fid & 3;
        int k0 = 32 * ks + (l >> 4) * 8;
        int col = 16 * ct + (l & 15);
#pragma unroll
        for (int j = 0; j < 8; j++) {
            float v = Wf[(size_t)col * FIN + k0 + j];
            ushort_t h = f2bf(v);
            size_t idx = ((size_t)fid * 64 + l) * 8 + j;
            Wfh[idx] = h;
            Wfl[idx] = f2bf(v - bf2f(h));
        }
    }
}

// ---------- split-bf16 A-fragment conversion ----------

__device__ __forceinline__ void cvt8(float4 x, float4 y, short8v& hi, short8v& lo) {
    union { short8v v; ushort_t u[8]; } H, L;
    float f[8] = {x.x, x.y, x.z, x.w, y.x, y.y, y.z, y.w};
#pragma unroll
    for (int j = 0; j < 8; j++) {
        ushort_t h = f2bf(f[j]);
        H.u[j] = h;
        L.u[j] = f2bf(f[j] - bf2f(h));
    }
    hi = H.v; lo = L.v;
}

// ---------- lin+gemm (layer 0): h = relu(x@Wf^T+bf) then gemm, 256 thr / 64 nodes ----------

__global__ __launch_bounds__(256) void lin_gemm(
    const float* __restrict__ xin,
    const ushort_t* __restrict__ WfH, const ushort_t* __restrict__ WfL,
    const ushort_t* __restrict__ Bph, const ushort_t* __restrict__ Bpl,
    const float* __restrict__ bfv, const float* __restrict__ bias,
    float* __restrict__ hrootOut, ushort_t* __restrict__ g0Out, ushort_t* __restrict__ g1Out,
    int N)
{
    __shared__ float sout[4][16][100];
    int t = threadIdx.x;
    int l = t & 63;
    int w = t >> 6;

    int slab = blockIdx.x * 64 + w * 16;
    int row = slab + (l & 15);
    if (row >= N) row = N - 1;
    const float* xrow = xin + (size_t)row * FIN + ((l >> 4) * 8);
    short8v ah4[4], al4[4];
#pragma unroll
    for (int ks = 0; ks < 4; ks++) {
        float4 xa = *(const float4*)(xrow + 32 * ks);
        float4 xb = *(const float4*)(xrow + 32 * ks + 4);
        cvt8(xa, xb, ah4[ks], al4[ks]);
    }
#pragma unroll
    for (int ct = 0; ct < 6; ct++) {
        f32x4 hh = {0.f,0.f,0.f,0.f}, hl_ = {0.f,0.f,0.f,0.f}, lh = {0.f,0.f,0.f,0.f};
#pragma unroll
        for (int ks = 0; ks < 4; ks++) {
            size_t base = ((size_t)(ct * 4 + ks) * 64 + l) * 8;
            short8v bh = *(const short8v*)(WfH + base);
            short8v bl = *(const short8v*)(WfL + base);
            hh  = MFMA16(ah4[ks], bh, hh, 0, 0, 0);
            hl_ = MFMA16(ah4[ks], bl, hl_, 0, 0, 0);
            lh  = MFMA16(al4[ks], bh, lh, 0, 0, 0);
        }
        f32x4 acc = hh + hl_ + lh;
        int col = ct * 16 + (l & 15);
        float bv = bfv[col];
        int lr0 = (l >> 4) * 4;
#pragma unroll
        for (int r = 0; r < 4; r++) {
            float v = acc[r] + bv;
            sout[w][lr0 + r][col] = v > 0.f ? v : 0.f;
        }
    }
    __syncthreads();

    const float* srow = &sout[w][l & 15][0];
    int mbase = blockIdx.x * 64 + w * 16 + ((l >> 4) << 2);
    int k0 = (l >> 4) * 8;
    short8v ah[3], al[3];
#pragma unroll
    for (int ks = 0; ks < 3; ks++) {
        float4 xa = *(const float4*)(srow + k0 + 32 * ks);
        float4 xb = *(const float4*)(srow + k0 + 32 * ks + 4);
        cvt8(xa, xb, ah[ks], al[ks]);
    }
    for (int ct = 0; ct < 18; ct++) {
        f32x4 hh = {0.f,0.f,0.f,0.f}, hl_ = {0.f,0.f,0.f,0.f}, lh = {0.f,0.f,0.f,0.f};
#pragma unroll
        for (int ks = 0; ks < 3; ks++) {
            size_t base = ((size_t)(ct * 3 + ks) * 64 + l) * 8;
            short8v bh = *(const short8v*)(Bph + base);
            short8v bl = *(const short8v*)(Bpl + base);
            hh  = MFMA16(ah[ks], bh, hh, 0, 0, 0);
            hl_ = MFMA16(ah[ks], bl, hl_, 0, 0, 0);
            lh  = MFMA16(al[ks], bh, lh, 0, 0, 0);
        }
        f32x4 acc = hh + hl_ + lh;
        int mat = ct / 6;
        int col = (ct % 6) * 16 + (l & 15);
        if (mat == 0) {
            float bv = bias[col];
#pragma unroll
            for (int r = 0; r < 4; r++) {
                int m = mbase + r;
                if (m < N) hrootOut[(size_t)m * DN + col] = acc[r] + bv;
            }
        } else {
            ushort_t* g = (mat == 1) ? g0Out : g1Out;
#pragma unroll
            for (int r = 0; r < 4; r++) {
                int m = mbase + r;
                if (m < N) g[(size_t)m * DN + col] = f2bf(acc[r]);
            }
        }
    }
}

// ---------- fused gather(+gemm) layer: 512 thr / 16 nodes ----------
// Gather: 32 lanes per node (lanes 0-15 even edges, 16-31 odd edges; feature
// slice 6 floats per lane), r0/r1 edge lists interleaved -> 8 loads in flight;
// halves combined with one __shfl_xor(16). GEMM (if enabled): 18 col-tiles
// split 3/3/2/2/2/2/2/2 across the 8 waves.

template <int GEMM>
__global__ __launch_bounds__(512, 4) void layer_kernel(
    const float* __restrict__ hrootIn,
    const uint_t* __restrict__ g0In, const uint_t* __restrict__ g1In,
    const int* __restrict__ rowstart, const int* __restrict__ cnt,
    const int* __restrict__ srcs,
    const ushort_t* __restrict__ Bph, const ushort_t* __restrict__ Bpl,
    const float* __restrict__ bias,
    float* __restrict__ hrootOut, ushort_t* __restrict__ g0Out, ushort_t* __restrict__ g1Out,
    float* __restrict__ dout, int N)
{
    __shared__ float sout[16][100];   // pad breaks power-of-2 bank stride
    int t = threadIdx.x;

    // ---- gather phase ----
    {
        int grp = t >> 5;
        int l32 = t & 31;
        int j = l32 & 15;       // feature slot (6 floats)
        int sub = l32 >> 4;     // edge parity
        int n = blockIdx.x * 16 + grp;
        bool valid = n < N;
        int nc = valid ? n : N - 1;
        int c0 = valid ? cnt[nc] : 0;
        int b0 = valid ? rowstart[nc] : 0;
        int c1 = valid ? cnt[N + nc] : 0;
        int b1 = valid ? rowstart[N + nc] : 0;

        float2 ph0, ph1, ph2;
        if (sub == 0) {   // issue early; consumed after the loop
            const float* hr = hrootIn + (size_t)nc * DN + 6 * j;
            ph0 = *(const float2*)hr;
            ph1 = *(const float2*)(hr + 2);
            ph2 = *(const float2*)(hr + 4);
        }

        float sA[6] = {0.f,0.f,0.f,0.f,0.f,0.f};
        float sB[6] = {0.f,0.f,0.f,0.f,0.f,0.f};
        const int* q0 = srcs + b0 + sub;
        const int* q1 = srcs + b1 + sub;
        int m0 = (c0 + 1 - sub) >> 1;   // edges this lane handles (parity sub)
        int m1 = (c1 + 1 - sub) >> 1;
        int i0 = 0, i1 = 0;
        while (i0 + 4 <= m0 && i1 + 4 <= m1) {
            U3 a0 = ldrow(g0In, q0[0], j), a1 = ldrow(g0In, q0[2], j);
            U3 a2 = ldrow(g0In, q0[4], j), a3 = ldrow(g0In, q0[6], j);
            U3 b0v = ldrow(g1In, q1[0], j), b1v = ldrow(g1In, q1[2], j);
            U3 b2v = ldrow(g1In, q1[4], j), b3v = ldrow(g1In, q1[6], j);
            acc6(sA, a0); acc6(sA, a1); acc6(sA, a2); acc6(sA, a3);
            acc6(sB, b0v); acc6(sB, b1v); acc6(sB, b2v); acc6(sB, b3v);
            q0 += 8; q1 += 8; i0 += 4; i1 += 4;
        }
        while (i0 + 4 <= m0) {
            U3 a0 = ldrow(g0In, q0[0], j), a1 = ldrow(g0In, q0[2], j);
            U3 a2 = ldrow(g0In, q0[4], j), a3 = ldrow(g0In, q0[6], j);
            acc6(sA, a0); acc6(sA, a1); acc6(sA, a2); acc6(sA, a3);
            q0 += 8; i0 += 4;
        }
        while (i1 + 4 <= m1) {
            U3 b0v = ldrow(g1In, q1[0], j), b1v = ldrow(g1In, q1[2], j);
            U3 b2v = ldrow(g1In, q1[4], j), b3v = ldrow(g1In, q1[6], j);
            acc6(sB, b0v); acc6(sB, b1v); acc6(sB, b2v); acc6(sB, b3v);
            q1 += 8; i1 += 4;
        }
        for (; i0 < m0; i0++) { U3 v = ldrow(g0In, q0[0], j); acc6(sA, v); q0 += 2; }
        for (; i1 < m1; i1++) { U3 v = ldrow(g1In, q1[0], j); acc6(sB, v); q1 += 2; }

#pragma unroll
        for (int k = 0; k < 6; k++) {
            sA[k] += __shfl_xor(sA[k], 16);
            sB[k] += __shfl_xor(sB[k], 16);
        }
        if (sub == 0) {
            float inv0 = (c0 > 0) ? 1.f / (float)c0 : 0.f;
            float inv1 = (c1 > 0) ? 1.f / (float)c1 : 0.f;
            float o0 = fmaxf(ph0.x + sA[0] * inv0 + sB[0] * inv1, 0.f);
            float o1 = fmaxf(ph0.y + sA[1] * inv0 + sB[1] * inv1, 0.f);
            float o2 = fmaxf(ph1.x + sA[2] * inv0 + sB[2] * inv1, 0.f);
            float o3 = fmaxf(ph1.y + sA[3] * inv0 + sB[3] * inv1, 0.f);
            float o4 = fmaxf(ph2.x + sA[4] * inv0 + sB[4] * inv1, 0.f);
            float o5 = fmaxf(ph2.y + sA[5] * inv0 + sB[5] * inv1, 0.f);
            if constexpr (GEMM) {
                float* dr = &sout[grp][6 * j];
                dr[0]=o0; dr[1]=o1; dr[2]=o2; dr[3]=o3; dr[4]=o4; dr[5]=o5;
            } else {
                if (valid) {
                    float* dr = dout + (size_t)n * DN + 6 * j;
                    *(float2*)(dr)     = make_float2(o0, o1);
                    *(float2*)(dr + 2) = make_float2(o2, o3);
                    *(float2*)(dr + 4) = make_float2(o4, o5);
                }
            }
        }
    }

    if constexpr (!GEMM) return;
    __syncthreads();

    // ---- gemm phase ----
    {
        int l = t & 63;
        int w = t >> 6;
        const float* srow = &sout[l & 15][0];
        int mbase = blockIdx.x * 16 + ((l >> 4) << 2);
        int k0 = (l >> 4) * 8;
        short8v ah[3], al[3];
#pragma unroll
        for (int ks = 0; ks < 3; ks++) {
            float4 xa = *(const float4*)(srow + k0 + 32 * ks);
            float4 xb = *(const float4*)(srow + k0 + 32 * ks + 4);
            cvt8(xa, xb, ah[ks], al[ks]);
        }
        int ctC = (w < 2) ? 3 : 2;
        int ctS = (w < 2) ? 3 * w : 6 + 2 * (w - 2);
        for (int ci = 0; ci < ctC; ci++) {
            int ct = ctS + ci;
            f32x4 hh = {0.f,0.f,0.f,0.f}, hl_ = {0.f,0.f,0.f,0.f}, lh = {0.f,0.f,0.f,0.f};
#pragma unroll
            for (int ks = 0; ks < 3; ks++) {
                size_t base = ((size_t)(ct * 3 + ks) * 64 + l) * 8;
                short8v bh = *(const short8v*)(Bph + base);
                short8v bl = *(const short8v*)(Bpl + base);
                hh  = MFMA16(ah[ks], bh, hh, 0, 0, 0);
                hl_ = MFMA16(ah[ks], bl, hl_, 0, 0, 0);
                lh  = MFMA16(al[ks], bh, lh, 0, 0, 0);
            }
            f32x4 acc = hh + hl_ + lh;
            int mat = ct / 6;
            int col = (ct % 6) * 16 + (l & 15);
            if (mat == 0) {
                float bv = bias[col];
#pragma unroll
                for (int r = 0; r < 4; r++) {
                    int m = mbase + r;
                    if (m < N) hrootOut[(size_t)m * DN + col] = acc[r] + bv;
                }
            } else {
                ushort_t* g = (mat == 1) ? g0Out : g1Out;
#pragma unroll
                for (int r = 0; r < 4; r++) {
                    int m = mbase + r;
                    if (m < N) g[(size_t)m * DN + col] = f2bf(acc[r]);
                }
            }
        }
    }
}

extern "C" void kernel_launch(void* const* d_in, const int* in_sizes, int n_in,
                              void* d_out, int out_size, void* d_ws, size_t ws_size,
                              hipStream_t stream) {
    const float* x    = (const float*)d_in[0];
    const int*   ei   = (const int*)d_in[1];
    const float* ea   = (const float*)d_in[2];
    const float* Wf   = (const float*)d_in[3];
    const float* bf   = (const float*)d_in[4];
    const float* W    = (const float*)d_in[5];
    const float* root = (const float*)d_in[6];
    const float* bias = (const float*)d_in[7];
    float* out = (float*)d_out;

    int N = in_sizes[0] / FIN;  // 50000
    int E = in_sizes[1] / 2;    // 800000
    int nbins = 2 * N;
    int PS = (N + 7) / 8;       // dst partition size

    int* cnt      = (int*)d_ws;            // [2N]
    int* total    = cnt + nbins;           // [1]
    int* rowstart = cnt + nbins + 4;       // [2N]
    int* fillptr  = rowstart + nbins;      // [2N]
    int* srcs     = fillptr + nbins;       // [E]
    uint2* kd     = (uint2*)(srcs + E);    // [E] packed (dst|r, src)
    ushort_t* Bph = (ushort_t*)(kd + E);   // [54*512]
    ushort_t* Bpl = Bph + 54 * 512;        // [54*512]
    ushort_t* Wfh = Bpl + 54 * 512;        // [24*512]
    ushort_t* Wfl = Wfh + 24 * 512;        // [24*512]
    float* hrootA = (float*)(Wfl + 24 * 512);      // [N*96] f32
    ushort_t* g0A = (ushort_t*)(hrootA + (size_t)N * DN);  // [N*96] bf16
    ushort_t* g1A = g0A + (size_t)N * DN;
    float* hrootB = (float*)(g1A + (size_t)N * DN);        // [N*96] f32
    ushort_t* g0B = (ushort_t*)(hrootB + (size_t)N * DN);
    ushort_t* g1B = g0B + (size_t)N * DN;

    hipMemsetAsync(cnt, 0, (size_t)(nbins + 1) * sizeof(int), stream);

    hist_kernel<<<(E + 255) / 256, 256, 0, stream>>>(ei, ea, cnt, kd, E, N);
    offsets_kernel<<<(nbins + 255) / 256, 256, 0, stream>>>(cnt, total, rowstart, fillptr, nbins);
    int nchunk = (E + 2047) / 2048;
    fill_part<<<nchunk * 8, 256, 0, stream>>>(kd, fillptr, srcs, E, N, PS);
    pack_all<<<78, 64, 0, stream>>>(root, W, Wf, Bph, Bpl, Wfh, Wfl);

    int blk64 = (N + 63) / 64;
    int blk16 = (N + 15) / 16;

    // L0: lin+gemm from x -> set A
    lin_gemm<<<blk64, 256, 0, stream>>>(
        x, Wfh, Wfl, Bph, Bpl, bf, bias, hrootA, g0A, g1A, N);
    // L1: gather A -> gemm -> set B
    layer_kernel<1><<<blk16, 512, 0, stream>>>(
        hrootA, (const uint_t*)g0A, (const uint_t*)g1A, rowstart, cnt, srcs,
        Bph, Bpl, bias, hrootB, g0B, g1B, nullptr, N);
    // L2: gather B -> gemm -> set A
    layer_kernel<1><<<blk16, 512, 0, stream>>>(
        hrootB, (const uint_t*)g0B, (const uint_t*)g1B, rowstart, cnt, srcs,
        Bph, Bpl, bias, hrootA, g0A, g1A, nullptr, N);
    // L3: gather A -> d_out
    layer_kernel<0><<<blk16, 512, 0, stream>>>(
        hrootA, (const uint_t*)g0A, (const uint_t*)g1A, rowstart, cnt, srcs,
        nullptr, nullptr, nullptr, nullptr, nullptr, nullptr, out, N);
}